// Round 3
// baseline (32238.522 us; speedup 1.0000x reference)
//
#include <hip/hip_runtime.h>
#include <hip/hip_bf16.h>
#include <math.h>

#define B_    2
#define S_    2048
#define DIN   2048
#define DOUT  2048
#define H_    16
#define RD_   64
#define L_    512
#define HD_   128
#define BS_   (B_*S_)   // 4096

// ---------------------------------------------------------------------------
// Generic NT GEMM: C[m][n] = sum_k A[m][k] * B[n][k]
// Requires M,N % 64 == 0, K % 16 == 0. 64x64 tile, 256 threads, 4x4 micro-tile.
// ---------------------------------------------------------------------------
__global__ __launch_bounds__(256) void gemm_nt(
    const float* __restrict__ A, const float* __restrict__ Bm, float* __restrict__ C,
    int M, int N, int K, int lda, int ldb, int ldc)
{
    __shared__ float As[16][68];   // [k][m], pad 68
    __shared__ float Bs[16][68];   // [k][n]

    const int tid = threadIdx.x;
    const int tx = tid & 15, ty = tid >> 4;
    const int m0 = blockIdx.y << 6, n0 = blockIdx.x << 6;

    float acc[4][4];
    #pragma unroll
    for (int i = 0; i < 4; i++)
        #pragma unroll
        for (int j = 0; j < 4; j++) acc[i][j] = 0.f;

    const int kk_l = tid & 15;
    const int mm_l = tid >> 4;

    for (int k0 = 0; k0 < K; k0 += 16) {
        #pragma unroll
        for (int i = 0; i < 4; i++) {
            As[kk_l][mm_l + 16*i] = A [(long long)(m0 + mm_l + 16*i) * lda + k0 + kk_l];
            Bs[kk_l][mm_l + 16*i] = Bm[(long long)(n0 + mm_l + 16*i) * ldb + k0 + kk_l];
        }
        __syncthreads();
        #pragma unroll
        for (int kk = 0; kk < 16; kk++) {
            float4 a4 = *(const float4*)&As[kk][ty << 2];
            float4 b4 = *(const float4*)&Bs[kk][tx << 2];
            float a[4] = {a4.x, a4.y, a4.z, a4.w};
            float b[4] = {b4.x, b4.y, b4.z, b4.w};
            #pragma unroll
            for (int i = 0; i < 4; i++)
                #pragma unroll
                for (int j = 0; j < 4; j++)
                    acc[i][j] += a[i] * b[j];
        }
        __syncthreads();
    }

    #pragma unroll
    for (int i = 0; i < 4; i++) {
        float4 v = {acc[i][0], acc[i][1], acc[i][2], acc[i][3]};
        *(float4*)&C[(long long)(m0 + (ty << 2) + i) * ldc + n0 + (tx << 2)] = v;
    }
}

// ---------------------------------------------------------------------------
// RMSNorm in place over rows of length 512, times weight.
// ---------------------------------------------------------------------------
__global__ __launch_bounds__(256) void rmsnorm_kernel(float* __restrict__ ckv,
                                                      const float* __restrict__ w)
{
    const int row = blockIdx.x;
    const int tid = threadIdx.x;
    float* p = ckv + (long long)row * L_;
    float v0 = p[tid], v1 = p[tid + 256];
    float ss = v0 * v0 + v1 * v1;
    #pragma unroll
    for (int o = 32; o >= 1; o >>= 1) ss += __shfl_xor(ss, o);
    __shared__ float wsum[4];
    if ((tid & 63) == 0) wsum[tid >> 6] = ss;
    __syncthreads();
    float tot = wsum[0] + wsum[1] + wsum[2] + wsum[3];
    float scale = rsqrtf(tot * (1.0f / (float)L_) + 1e-6f);
    p[tid]       = v0 * scale * w[tid];
    p[tid + 256] = v1 * scale * w[tid + 256];
}

// ---------------------------------------------------------------------------
// w_uk_t[h][l][d] = W_UK[h*HD + d][l]
// ---------------------------------------------------------------------------
__global__ __launch_bounds__(256) void transpose_wuk(const float* __restrict__ W_UK,
                                                     float* __restrict__ w_uk_t)
{
    long long idx = (long long)blockIdx.x * 256 + threadIdx.x;  // over H*L*HD
    int d = (int)(idx % HD_);
    long long t = idx / HD_;
    int l = (int)(t % L_);
    int h = (int)(t / L_);
    w_uk_t[idx] = W_UK[(long long)(h * HD_ + d) * L_ + l];
}

// ---------------------------------------------------------------------------
// RoPE (GPT-NeoX style), IN PLACE on q_raw rope cols and kr_raw.
// ---------------------------------------------------------------------------
__global__ __launch_bounds__(256) void rope_kernel(float* __restrict__ q_raw,
                                                   float* __restrict__ kr_raw,
                                                   const int* __restrict__ offp)
{
    const int offset = offp[0];
    long long idx = (long long)blockIdx.x * 256 + threadIdx.x;  // over (B*S)*H*32
    int r = (int)(idx & 31);
    long long t = idx >> 5;
    int h = (int)(t % H_);
    long long m = t / H_;                 // m = b*S + s
    int s = (int)(m % S_);

    float inv = (float)exp(-9.210340371976184 * ((double)r / 32.0)); // 10000^(-r/32)
    float ang = (float)(offset + s) * inv;
    float sn, cs;
    sincosf(ang, &sn, &cs);

    float* q = q_raw + m * 3072 + DOUT + h * RD_;
    float x1 = q[r], x2 = q[r + 32];
    q[r]      = x1 * cs - x2 * sn;
    q[r + 32] = x2 * cs + x1 * sn;

    float* kk = kr_raw + m * (H_ * RD_) + h * RD_;
    x1 = kk[r]; x2 = kk[r + 32];
    kk[r]      = x1 * cs - x2 * sn;
    kk[r + 32] = x2 * cs + x1 * sn;
}

// ---------------------------------------------------------------------------
// Fused flash latent attention.
// Grid: (S/32, B*H). Block: 512 threads = 32 Q-rows x 16 lane-chunks.
// Thread (rl,j) owns latent cols { k*64 + j*4 + i : k<8, i<4 } (32 dims).
// Per-thread state: qa[8][4]+acc[8][4]+qr[4] ~= 90 floats -> fits 128 VGPR,
// no scratch spill (R1's 13.4 GB WRITE_SIZE was spill traffic at 8 lanes/row).
// ---------------------------------------------------------------------------
__global__ __launch_bounds__(512, 2) void flash_kernel(
    const float* __restrict__ q_raw,   // [BS][3072] (rope cols already rotated)
    const float* __restrict__ c_kv,    // [BS][512]
    const float* __restrict__ kr_raw,  // [BS][1024] (rotated, head-major cols)
    const float* __restrict__ w_uk_t,  // [H][512][128]
    const float* __restrict__ W_UV,    // [2048][512]
    const int* __restrict__ offp,
    float* __restrict__ ctx)           // [BS][2048]
{
    __shared__ float smem[32 * 516];   // 66,048 B; unioned:
    float* ckv_s = smem;               //   main: [16][512]
    float* kr_s  = smem + 8192;        //   main: [16][64]
                                       //   prologue: qc [32][132]
                                       //   epilogue: acc [32][516]

    const int offset = offp[0];
    const int bh = blockIdx.y;
    const int b = bh >> 4, h = bh & 15;
    const int r0 = blockIdx.x * 32;
    const int tid = threadIdx.x;
    const int rl = tid >> 4;          // local Q-row 0..31
    const int j  = tid & 15;          // chunk 0..15
    const int srow = r0 + rl;
    const long long mrow = (long long)b * S_ + srow;

    // ---- prologue: qc tile -> LDS ----
    {
        const float* src = q_raw + mrow * 3072 + h * HD_ + j * 8;
        float* dst = &smem[rl * 132 + j * 8];
        ((float4*)dst)[0] = ((const float4*)src)[0];
        ((float4*)dst)[1] = ((const float4*)src)[1];
    }
    __syncthreads();

    // qa[k][i] = q_abs col (k*64 + j*4 + i)
    float qa[8][4];
    #pragma unroll
    for (int k = 0; k < 8; k++)
        #pragma unroll
        for (int i = 0; i < 4; i++) qa[k][i] = 0.f;

    for (int dc = 0; dc < 128; dc += 16) {
        float4 qc[4];
        #pragma unroll
        for (int i = 0; i < 4; i++) qc[i] = *(const float4*)&smem[rl * 132 + dc + i * 4];
        #pragma unroll
        for (int k = 0; k < 8; k++) {
            #pragma unroll
            for (int i = 0; i < 4; i++) {
                const float4* wp = (const float4*)
                    (w_uk_t + ((long long)(h * L_ + k * 64 + (j << 2) + i)) * HD_ + dc);
                float s = 0.f;
                #pragma unroll
                for (int d4 = 0; d4 < 4; d4++) {
                    float4 w4 = wp[d4];
                    s += qc[d4].x * w4.x + qc[d4].y * w4.y
                       + qc[d4].z * w4.z + qc[d4].w * w4.w;
                }
                qa[k][i] += s;
            }
        }
    }

    // q_rope fragment: cols j*4..j*4+3 of the 64 rope dims
    float qr[4];
    {
        float4 v = *(const float4*)(q_raw + mrow * 3072 + DOUT + h * RD_ + (j << 2));
        qr[0] = v.x; qr[1] = v.y; qr[2] = v.z; qr[3] = v.w;
    }

    float acc[8][4];
    #pragma unroll
    for (int k = 0; k < 8; k++)
        #pragma unroll
        for (int i = 0; i < 4; i++) acc[k][i] = 0.f;

    float m = -INFINITY, l = 0.f;
    const float scale = rsqrtf((float)(HD_ + RD_));

    int tmax = r0 + 32 + offset;
    if (tmax > S_) tmax = S_;

    for (int t0 = 0; t0 < tmax; t0 += 16) {
        __syncthreads();   // previous-iter (or prologue) LDS reads done
        const int avail = S_ - t0;
        {
            const float4* csrc4 = (const float4*)(c_kv + ((long long)b * S_ + t0) * L_);
            float4* cdst4 = (float4*)ckv_s;
            #pragma unroll
            for (int i = 0; i < 4; i++) {
                int f4 = i * 512 + tid;
                cdst4[f4] = ((f4 >> 7) < avail) ? csrc4[f4] : make_float4(0.f,0.f,0.f,0.f);
            }
            if (tid < 256) {
                int krow = tid >> 4, kcol = (tid & 15) << 2;
                const float4 kv = (krow < avail)
                    ? *(const float4*)(kr_raw + ((long long)b * S_ + t0 + krow) * (H_*RD_) + h * RD_ + kcol)
                    : make_float4(0.f,0.f,0.f,0.f);
                *(float4*)&kr_s[krow * RD_ + kcol] = kv;
            }
        }
        __syncthreads();

        float sc[16];
        #pragma unroll
        for (int ti = 0; ti < 16; ti++) {
            const float* cvrow = &ckv_s[ti * L_];
            float s = 0.f;
            #pragma unroll
            for (int k = 0; k < 8; k++) {
                float4 v = *(const float4*)(cvrow + (j << 2) + (k << 6));
                s += qa[k][0] * v.x + qa[k][1] * v.y + qa[k][2] * v.z + qa[k][3] * v.w;
            }
            {
                float4 v = *(const float4*)(&kr_s[ti * RD_] + (j << 2));
                s += qr[0] * v.x + qr[1] * v.y + qr[2] * v.z + qr[3] * v.w;
            }
            s += __shfl_xor(s, 1);
            s += __shfl_xor(s, 2);
            s += __shfl_xor(s, 4);
            s += __shfl_xor(s, 8);
            sc[ti] = ((t0 + ti) <= (srow + offset)) ? s * scale : -INFINITY;
        }

        float mt = sc[0];
        #pragma unroll
        for (int ti = 1; ti < 16; ti++) mt = fmaxf(mt, sc[ti]);
        float mnew = fmaxf(m, mt);
        float alpha = __expf(m - mnew);
        float psum = 0.f;
        #pragma unroll
        for (int ti = 0; ti < 16; ti++) { sc[ti] = __expf(sc[ti] - mnew); psum += sc[ti]; }
        l = l * alpha + psum;
        m = mnew;

        #pragma unroll
        for (int k = 0; k < 8; k++)
            #pragma unroll
            for (int i = 0; i < 4; i++) acc[k][i] *= alpha;

        #pragma unroll
        for (int ti = 0; ti < 16; ti++) {
            const float pt = sc[ti];
            const float* cvrow = &ckv_s[ti * L_];
            #pragma unroll
            for (int k = 0; k < 8; k++) {
                float4 v = *(const float4*)(cvrow + (j << 2) + (k << 6));
                acc[k][0] += pt * v.x; acc[k][1] += pt * v.y;
                acc[k][2] += pt * v.z; acc[k][3] += pt * v.w;
            }
        }
    }

    // ---- epilogue: acc -> LDS [32][516], then ctx tile = acc @ W_UV[h]^T ----
    __syncthreads();
    const float inv_l = 1.0f / l;
    #pragma unroll
    for (int k = 0; k < 8; k++) {
        float4 v = {acc[k][0] * inv_l, acc[k][1] * inv_l,
                    acc[k][2] * inv_l, acc[k][3] * inv_l};
        *(float4*)&smem[rl * 516 + (k << 6) + (j << 2)] = v;
    }
    __syncthreads();

    // thread (rl,j) computes out cols j*8..j*8+7 of this head's 128
    float o[8];
    #pragma unroll
    for (int c = 0; c < 8; c++) o[c] = 0.f;
    const float* wv = W_UV + ((long long)(h * HD_ + j * 8)) * L_;
    for (int lc = 0; lc < 512; lc += 4) {
        float4 a4 = *(const float4*)&smem[rl * 516 + lc];
        #pragma unroll
        for (int c = 0; c < 8; c++) {
            float4 w4 = *(const float4*)&wv[(long long)c * L_ + lc];
            o[c] += a4.x * w4.x + a4.y * w4.y + a4.z * w4.z + a4.w * w4.w;
        }
    }
    float* cp = ctx + mrow * DOUT + h * HD_ + j * 8;
    #pragma unroll
    for (int c4 = 0; c4 < 2; c4++) {
        float4 v = {o[c4*4], o[c4*4+1], o[c4*4+2], o[c4*4+3]};
        ((float4*)cp)[c4] = v;
    }
}

// ---------------------------------------------------------------------------
extern "C" void kernel_launch(void* const* d_in, const int* in_sizes, int n_in,
                              void* d_out, int out_size, void* d_ws, size_t ws_size,
                              hipStream_t stream)
{
    const float* x       = (const float*)d_in[0];
    const float* W_DKV   = (const float*)d_in[1];
    const float* W_KRope = (const float*)d_in[2];
    const float* W_Q     = (const float*)d_in[3];
    const float* W_UK    = (const float*)d_in[4];
    const float* W_UV    = (const float*)d_in[5];
    const float* W_O     = (const float*)d_in[6];
    const float* kvnw    = (const float*)d_in[7];
    const int*   offp    = (const int*)d_in[8];
    float* out = (float*)d_out;

    float* ws = (float*)d_ws;
    float* c_kv   = ws;                      // 2,097,152   [B*S][512]
    float* kr_raw = c_kv   + 2097152;        // 4,194,304   [B*S][1024]
    float* q_raw  = kr_raw + 4194304;        // 12,582,912  [B*S][3072]
    float* w_uk_t = q_raw  + 12582912;       // 1,048,576   [H][512][128]
    float* ctx    = w_uk_t + 1048576;        // 8,388,608   [B*S][2048]
    // total: 28,311,552 floats = 108 MiB

    dim3 blk(256);

    // 1. c_kv_raw = x @ W_DKV^T    [4096 x 512], K=2048
    gemm_nt<<<dim3(512/64, 4096/64), blk, 0, stream>>>(
        x, W_DKV, c_kv, 4096, 512, 2048, 2048, 2048, 512);
    // 2. RMSNorm in place
    rmsnorm_kernel<<<4096, 256, 0, stream>>>(c_kv, kvnw);
    // 3. kr_raw = x @ W_KRope^T    [4096 x 1024]
    gemm_nt<<<dim3(1024/64, 4096/64), blk, 0, stream>>>(
        x, W_KRope, kr_raw, 4096, 1024, 2048, 2048, 2048, 1024);
    // 4. q_raw = x @ W_Q^T         [4096 x 3072]
    gemm_nt<<<dim3(3072/64, 4096/64), blk, 0, stream>>>(
        x, W_Q, q_raw, 4096, 3072, 2048, 2048, 2048, 3072);
    // 5. w_uk transpose
    transpose_wuk<<<4096, 256, 0, stream>>>(W_UK, w_uk_t);
    // 6. RoPE in place (q_raw rope cols, kr_raw)
    rope_kernel<<<8192, 256, 0, stream>>>(q_raw, kr_raw, offp);
    // 7. fused flash latent attention -> ctx
    flash_kernel<<<dim3(S_/32, B_*H_), dim3(512), 0, stream>>>(
        q_raw, c_kv, kr_raw, w_uk_t, W_UV, offp, ctx);
    // 8. out = ctx @ W_O^T         [4096 x 2048]
    gemm_nt<<<dim3(2048/64, 4096/64), blk, 0, stream>>>(
        ctx, W_O, out, 4096, 2048, 2048, 2048, 2048, 2048);
}

// Round 4
// 3649.450 us; speedup vs baseline: 8.8338x; 8.8338x over previous
//
#include <hip/hip_runtime.h>
#include <hip/hip_bf16.h>
#include <math.h>

#define B_    2
#define S_    2048
#define DIN   2048
#define DOUT  2048
#define H_    16
#define RD_   64
#define L_    512
#define HD_   128
#define BS_   (B_*S_)   // 4096

typedef __attribute__((ext_vector_type(8))) short bf16x8;
typedef __attribute__((ext_vector_type(4))) float f32x4;

__device__ __forceinline__ short f2bs(float f) {
    __hip_bfloat16 h = __float2bfloat16(f);
    return *reinterpret_cast<short*>(&h);
}

// ---------------------------------------------------------------------------
// Generic fp32 NT GEMM (unchanged): C[m][n] = sum_k A[m][k] * B[n][k]
// ---------------------------------------------------------------------------
__global__ __launch_bounds__(256) void gemm_nt(
    const float* __restrict__ A, const float* __restrict__ Bm, float* __restrict__ C,
    int M, int N, int K, int lda, int ldb, int ldc)
{
    __shared__ float As[16][68];
    __shared__ float Bs[16][68];

    const int tid = threadIdx.x;
    const int tx = tid & 15, ty = tid >> 4;
    const int m0 = blockIdx.y << 6, n0 = blockIdx.x << 6;

    float acc[4][4];
    #pragma unroll
    for (int i = 0; i < 4; i++)
        #pragma unroll
        for (int j = 0; j < 4; j++) acc[i][j] = 0.f;

    const int kk_l = tid & 15;
    const int mm_l = tid >> 4;

    for (int k0 = 0; k0 < K; k0 += 16) {
        #pragma unroll
        for (int i = 0; i < 4; i++) {
            As[kk_l][mm_l + 16*i] = A [(long long)(m0 + mm_l + 16*i) * lda + k0 + kk_l];
            Bs[kk_l][mm_l + 16*i] = Bm[(long long)(n0 + mm_l + 16*i) * ldb + k0 + kk_l];
        }
        __syncthreads();
        #pragma unroll
        for (int kk = 0; kk < 16; kk++) {
            float4 a4 = *(const float4*)&As[kk][ty << 2];
            float4 b4 = *(const float4*)&Bs[kk][tx << 2];
            float a[4] = {a4.x, a4.y, a4.z, a4.w};
            float b[4] = {b4.x, b4.y, b4.z, b4.w};
            #pragma unroll
            for (int i = 0; i < 4; i++)
                #pragma unroll
                for (int j = 0; j < 4; j++)
                    acc[i][j] += a[i] * b[j];
        }
        __syncthreads();
    }

    #pragma unroll
    for (int i = 0; i < 4; i++) {
        float4 v = {acc[i][0], acc[i][1], acc[i][2], acc[i][3]};
        *(float4*)&C[(long long)(m0 + (ty << 2) + i) * ldc + n0 + (tx << 2)] = v;
    }
}

// ---------------------------------------------------------------------------
// RMSNorm rows of 512 -> bf16 output
// ---------------------------------------------------------------------------
__global__ __launch_bounds__(256) void rmsnorm_bf(const float* __restrict__ ckv,
                                                  const float* __restrict__ w,
                                                  short* __restrict__ out)
{
    const int row = blockIdx.x;
    const int tid = threadIdx.x;
    const float* p = ckv + (long long)row * L_;
    float v0 = p[tid], v1 = p[tid + 256];
    float ss = v0 * v0 + v1 * v1;
    #pragma unroll
    for (int o = 32; o >= 1; o >>= 1) ss += __shfl_xor(ss, o);
    __shared__ float wsum[4];
    if ((tid & 63) == 0) wsum[tid >> 6] = ss;
    __syncthreads();
    float tot = wsum[0] + wsum[1] + wsum[2] + wsum[3];
    float scale = rsqrtf(tot * (1.0f / (float)L_) + 1e-6f);
    out[(long long)row * L_ + tid]       = f2bs(v0 * scale * w[tid]);
    out[(long long)row * L_ + tid + 256] = f2bs(v1 * scale * w[tid + 256]);
}

// ---------------------------------------------------------------------------
// c_kv_T[b][n][t] = c_kv_bf[b][t][n]   (bf16, tiled transpose)
// grid (S/64, 512/64, B)
// ---------------------------------------------------------------------------
__global__ __launch_bounds__(256) void ckv_transpose(const short* __restrict__ in,
                                                     short* __restrict__ out)
{
    __shared__ short tile[64][72];
    const int b = blockIdx.z, t0 = blockIdx.x * 64, n0 = blockIdx.y * 64;
    const int tid = threadIdx.x;
    #pragma unroll
    for (int i = 0; i < 16; i++) {
        int idx = i*256 + tid, r = idx >> 6, c = idx & 63;
        tile[r][c] = in[((long long)b*S_ + t0 + r)*512 + n0 + c];
    }
    __syncthreads();
    #pragma unroll
    for (int i = 0; i < 16; i++) {
        int idx = i*256 + tid, r = idx >> 6, c = idx & 63;
        out[((long long)b*512 + n0 + r)*2048 + t0 + c] = tile[c][r];
    }
}

// ---------------------------------------------------------------------------
// w_uk_bf[h][l][d] = bf16(W_UK[h*HD + d][l])
// ---------------------------------------------------------------------------
__global__ __launch_bounds__(256) void transpose_wuk_bf(const float* __restrict__ W_UK,
                                                        short* __restrict__ w_uk_bf)
{
    long long idx = (long long)blockIdx.x * 256 + threadIdx.x;  // H*L*HD
    int d = (int)(idx % HD_);
    long long t = idx / HD_;
    int l = (int)(t % L_);
    int h = (int)(t / L_);
    w_uk_bf[idx] = f2bs(W_UK[(long long)(h * HD_ + d) * L_ + l]);
}

// ---------------------------------------------------------------------------
__global__ __launch_bounds__(256) void cast_wuv(const float* __restrict__ in,
                                                short* __restrict__ out)
{
    long long idx = (long long)blockIdx.x * 256 + threadIdx.x;  // 2048*512
    out[idx] = f2bs(in[idx]);
}

// ---------------------------------------------------------------------------
// RoPE in place on q_raw (fp32); kr -> kr_bf (bf16, head-major cols)
// ---------------------------------------------------------------------------
__global__ __launch_bounds__(256) void rope_kernel(float* __restrict__ q_raw,
                                                   const float* __restrict__ kr,
                                                   short* __restrict__ kr_bf,
                                                   const int* __restrict__ offp)
{
    const int offset = offp[0];
    long long idx = (long long)blockIdx.x * 256 + threadIdx.x;  // (B*S)*H*32
    int r = (int)(idx & 31);
    long long t = idx >> 5;
    int h = (int)(t % H_);
    long long m = t / H_;
    int s = (int)(m % S_);

    float inv = (float)exp(-9.210340371976184 * ((double)r / 32.0));
    float ang = (float)(offset + s) * inv;
    float sn, cs;
    sincosf(ang, &sn, &cs);

    float* q = q_raw + m * 3072 + DOUT + h * RD_;
    float x1 = q[r], x2 = q[r + 32];
    q[r]      = x1 * cs - x2 * sn;
    q[r + 32] = x2 * cs + x1 * sn;

    const float* kk = kr + m * (H_ * RD_) + h * RD_;
    x1 = kk[r]; x2 = kk[r + 32];
    kr_bf[m * 1024 + h * RD_ + r]      = f2bs(x1 * cs - x2 * sn);
    kr_bf[m * 1024 + h * RD_ + r + 32] = f2bs(x2 * cs + x1 * sn);
}

// ---------------------------------------------------------------------------
// MFMA flash latent attention (bf16, 16x16x32 NT pattern).
// Grid (S/64, B*H), 256 threads = 4 waves; wave w owns q-rows [w*16, w*16+16).
// LDS 78,336 B: K-tile [32 tok][584] (content 0..511, rope 512..575)
//               V-tile [512 n][40] (tokens in cols 0..31) at short-offset 18688
//               P (wave-private) overlays K rows 0..4; Q/O tiles overlay all.
// Pitches 584/40/520 chosen so each b128 8-lane phase covers 32 banks once.
// ---------------------------------------------------------------------------
__global__ __launch_bounds__(256, 2) void flash_mfma(
    const float* __restrict__ q_raw,    // [BS][3072] fp32, rope cols rotated
    const short* __restrict__ c_kv_bf,  // [BS][512]  bf16
    const short* __restrict__ c_kv_T,   // [B][512][2048] bf16
    const short* __restrict__ kr_bf,    // [BS][1024] bf16, rotated
    const short* __restrict__ w_uk_bf,  // [H][512][128] bf16
    const short* __restrict__ w_uv_bf,  // [2048][512] bf16
    const int* __restrict__ offp,
    float* __restrict__ ctx)            // [BS][2048] fp32
{
    __shared__ short lds[39168];
    const int offset = offp[0];
    const int bh = blockIdx.y;
    const int b = bh >> 4, h = bh & 15;
    const int r0 = blockIdx.x * 64;
    const int tid = threadIdx.x;
    const int w = tid >> 6, lane = tid & 63;
    const int quad = lane >> 4, n16 = lane & 15;
    const float scale = rsqrtf((float)(HD_ + RD_));
    short* Vt = lds + 18688;

    // ---- prologue: q_abs = q_content @ w_uk^T via MFMA; write Q tile (scaled, bf16) ----
    {
        bf16x8 qc[4];
        const long long qrow = (long long)b*S_ + r0 + w*16 + n16;
        const float* qp = q_raw + qrow*3072 + h*HD_ + quad*8;
        #pragma unroll
        for (int ks = 0; ks < 4; ks++) {
            float4 a0 = *(const float4*)(qp + ks*32);
            float4 a1 = *(const float4*)(qp + ks*32 + 4);
            bf16x8 t;
            t[0]=f2bs(a0.x); t[1]=f2bs(a0.y); t[2]=f2bs(a0.z); t[3]=f2bs(a0.w);
            t[4]=f2bs(a1.x); t[5]=f2bs(a1.y); t[6]=f2bs(a1.z); t[7]=f2bs(a1.w);
            qc[ks] = t;
        }
        #pragma unroll 4
        for (int v = 0; v < 32; v++) {
            f32x4 a = {0.f,0.f,0.f,0.f};
            const short* wp = w_uk_bf + ((long long)(h*512 + v*16 + n16) << 7) + quad*8;
            #pragma unroll
            for (int ks = 0; ks < 4; ks++)
                a = __builtin_amdgcn_mfma_f32_16x16x32_bf16(
                        qc[ks], *(const bf16x8*)(wp + ks*32), a, 0, 0, 0);
            #pragma unroll
            for (int r = 0; r < 4; r++)
                lds[(w*16 + quad*4 + r)*584 + v*16 + n16] = f2bs(a[r]*scale);
        }
        // rope cols 512..575 of Q tile
        #pragma unroll
        for (int i = 0; i < 16; i++) {
            int idx = i*256 + tid, rr = idx >> 6, cc = idx & 63;
            float v = q_raw[((long long)b*S_ + r0 + rr)*3072 + DOUT + h*RD_ + cc];
            lds[rr*584 + 512 + cc] = f2bs(v*scale);
        }
    }
    __syncthreads();
    bf16x8 qf[18];
    {
        const int qb = (w*16 + n16)*584 + quad*8;
        #pragma unroll
        for (int ks = 0; ks < 18; ks++)
            qf[ks] = *(const bf16x8*)(lds + qb + ks*32);
    }

    f32x4 Oacc[32];
    #pragma unroll
    for (int v = 0; v < 32; v++) Oacc[v] = (f32x4){0.f,0.f,0.f,0.f};
    float mrun[4] = {-INFINITY,-INFINITY,-INFINITY,-INFINITY};
    float lrun[4] = {0.f,0.f,0.f,0.f};

    int tmax = r0 + 64 + offset;
    if (tmax > S_) tmax = S_;

    for (int t0 = 0; t0 < tmax; t0 += 32) {
        __syncthreads();   // prior-iter P/V reads (and Q-frag reads) complete
        // stage K content rows [32][512]
        #pragma unroll
        for (int i = 0; i < 8; i++) {
            int ch = i*256 + tid, row = ch >> 6, c = ch & 63;
            int tok = t0 + row;
            bf16x8 z = {0,0,0,0,0,0,0,0};
            *(bf16x8*)(lds + row*584 + c*8) = (tok < S_)
                ? *(const bf16x8*)(c_kv_bf + (((long long)b*S_ + tok) << 9) + c*8) : z;
        }
        // stage K rope cols [32][64]
        {
            int row = tid >> 3, c = tid & 7, tok = t0 + row;
            bf16x8 z = {0,0,0,0,0,0,0,0};
            *(bf16x8*)(lds + row*584 + 512 + c*8) = (tok < S_)
                ? *(const bf16x8*)(kr_bf + (((long long)b*S_ + tok) << 10) + h*RD_ + c*8) : z;
        }
        // stage V [512][32]
        #pragma unroll
        for (int i = 0; i < 8; i++) {
            int ch = i*256 + tid, n = ch >> 2, c = ch & 3;
            int tok8 = t0 + c*8;
            bf16x8 z = {0,0,0,0,0,0,0,0};
            *(bf16x8*)(Vt + n*40 + c*8) = (tok8 < S_)
                ? *(const bf16x8*)(c_kv_T + (((long long)b*512 + n) << 11) + tok8) : z;
        }
        __syncthreads();

        // scores: S[16 q][32 tok] per wave
        f32x4 Sf[2];
        #pragma unroll
        for (int nt = 0; nt < 2; nt++) {
            f32x4 a = {0.f,0.f,0.f,0.f};
            const int kb = (nt*16 + n16)*584 + quad*8;
            #pragma unroll
            for (int ks = 0; ks < 18; ks++)
                a = __builtin_amdgcn_mfma_f32_16x16x32_bf16(
                        qf[ks], *(const bf16x8*)(lds + kb + ks*32), a, 0, 0, 0);
            Sf[nt] = a;
        }
        // online softmax (rows quad*4+r, token cols across the 16 lanes of the quad)
        float p0[4], p1[4], alpha[4];
        #pragma unroll
        for (int r = 0; r < 4; r++) {
            int srow = r0 + w*16 + quad*4 + r;
            int tA = t0 + n16, tB = t0 + 16 + n16;
            float sA = (tA <= srow + offset && tA < S_) ? Sf[0][r] : -INFINITY;
            float sB = (tB <= srow + offset && tB < S_) ? Sf[1][r] : -INFINITY;
            float tm = fmaxf(sA, sB);
            tm = fmaxf(tm, __shfl_xor(tm, 1));
            tm = fmaxf(tm, __shfl_xor(tm, 2));
            tm = fmaxf(tm, __shfl_xor(tm, 4));
            tm = fmaxf(tm, __shfl_xor(tm, 8));
            float mn = fmaxf(mrun[r], tm);
            float al = __expf(mrun[r] - mn);
            float eA = __expf(sA - mn), eB = __expf(sB - mn);
            float ps = eA + eB;
            ps += __shfl_xor(ps, 1);
            ps += __shfl_xor(ps, 2);
            ps += __shfl_xor(ps, 4);
            ps += __shfl_xor(ps, 8);
            lrun[r] = lrun[r]*al + ps;
            mrun[r] = mn;
            alpha[r] = al; p0[r] = eA; p1[r] = eB;
        }
        #pragma unroll
        for (int v = 0; v < 32; v++) {
            Oacc[v][0] *= alpha[0]; Oacc[v][1] *= alpha[1];
            Oacc[v][2] *= alpha[2]; Oacc[v][3] *= alpha[3];
        }
        __syncthreads();   // all waves done reading K before P overlays it

        // P (wave-private, [16 q][40] at short-offset w*640), then PV
        #pragma unroll
        for (int r = 0; r < 4; r++) {
            lds[w*640 + (quad*4 + r)*40 + n16]      = f2bs(p0[r]);
            lds[w*640 + (quad*4 + r)*40 + 16 + n16] = f2bs(p1[r]);
        }
        bf16x8 pf = *(const bf16x8*)(lds + w*640 + n16*40 + quad*8);
        #pragma unroll
        for (int v = 0; v < 32; v++) {
            bf16x8 vb = *(const bf16x8*)(Vt + (v*16 + n16)*40 + quad*8);
            Oacc[v] = __builtin_amdgcn_mfma_f32_16x16x32_bf16(pf, vb, Oacc[v], 0, 0, 0);
        }
    }

    // ---- epilogue: ctx = (O / l) @ W_UV^T via MFMA ----
    __syncthreads();
    float inv[4];
    #pragma unroll
    for (int r = 0; r < 4; r++) inv[r] = 1.0f / lrun[r];
    #pragma unroll
    for (int v = 0; v < 32; v++) {
        #pragma unroll
        for (int r = 0; r < 4; r++)
            lds[(w*16 + quad*4 + r)*520 + v*16 + n16] = f2bs(Oacc[v][r]*inv[r]);
    }
    __syncthreads();
    f32x4 cacc[8];
    #pragma unroll
    for (int d = 0; d < 8; d++) cacc[d] = (f32x4){0.f,0.f,0.f,0.f};
    const int ob = (w*16 + n16)*520 + quad*8;
    for (int ks = 0; ks < 16; ks++) {
        bf16x8 of = *(const bf16x8*)(lds + ob + ks*32);
        #pragma unroll
        for (int d = 0; d < 8; d++) {
            const short* wp = w_uv_bf + (((long long)(h*HD_ + d*16 + n16)) << 9) + ks*32 + quad*8;
            cacc[d] = __builtin_amdgcn_mfma_f32_16x16x32_bf16(of, *(const bf16x8*)wp, cacc[d], 0, 0, 0);
        }
    }
    #pragma unroll
    for (int d = 0; d < 8; d++) {
        #pragma unroll
        for (int r = 0; r < 4; r++) {
            long long row = (long long)b*S_ + r0 + w*16 + quad*4 + r;
            ctx[row*2048 + h*HD_ + d*16 + n16] = cacc[d][r];
        }
    }
}

// ---------------------------------------------------------------------------
extern "C" void kernel_launch(void* const* d_in, const int* in_sizes, int n_in,
                              void* d_out, int out_size, void* d_ws, size_t ws_size,
                              hipStream_t stream)
{
    const float* x       = (const float*)d_in[0];
    const float* W_DKV   = (const float*)d_in[1];
    const float* W_KRope = (const float*)d_in[2];
    const float* W_Q     = (const float*)d_in[3];
    const float* W_UK    = (const float*)d_in[4];
    const float* W_UV    = (const float*)d_in[5];
    const float* W_O     = (const float*)d_in[6];
    const float* kvnw    = (const float*)d_in[7];
    const int*   offp    = (const int*)d_in[8];
    float* out = (float*)d_out;

    float* ws = (float*)d_ws;
    float* c_kv    = ws;                       //  2,097,152 f  [BS][512] fp32
    float* kr      = c_kv  + 2097152;          //  4,194,304 f  [BS][1024] fp32
    float* q_raw   = kr    + 4194304;          // 12,582,912 f  [BS][3072] fp32
    float* ctx     = q_raw + 12582912;         //  8,388,608 f  [BS][2048] fp32
    short* c_kv_bf = (short*)(ctx + 8388608);  //  2,097,152 bf16
    short* c_kv_T  = c_kv_bf + 2097152;        //  2,097,152 bf16
    short* kr_bf   = c_kv_T  + 2097152;        //  4,194,304 bf16
    short* w_uk_bf = kr_bf   + 4194304;        //  1,048,576 bf16
    short* w_uv_bf = w_uk_bf + 1048576;        //  1,048,576 bf16
    // total = 124 MiB

    dim3 blk(256);

    // 1. c_kv_raw = x @ W_DKV^T
    gemm_nt<<<dim3(512/64, 4096/64), blk, 0, stream>>>(
        x, W_DKV, c_kv, 4096, 512, 2048, 2048, 2048, 512);
    // 2. RMSNorm -> bf16
    rmsnorm_bf<<<4096, 256, 0, stream>>>(c_kv, kvnw, c_kv_bf);
    // 3. c_kv transpose -> [B][512][S]
    ckv_transpose<<<dim3(32, 8, 2), blk, 0, stream>>>(c_kv_bf, c_kv_T);
    // 4. kr = x @ W_KRope^T
    gemm_nt<<<dim3(1024/64, 4096/64), blk, 0, stream>>>(
        x, W_KRope, kr, 4096, 1024, 2048, 2048, 2048, 1024);
    // 5. q_raw = x @ W_Q^T
    gemm_nt<<<dim3(3072/64, 4096/64), blk, 0, stream>>>(
        x, W_Q, q_raw, 4096, 3072, 2048, 2048, 2048, 3072);
    // 6. weights -> bf16
    transpose_wuk_bf<<<4096, 256, 0, stream>>>(W_UK, w_uk_bf);
    cast_wuv<<<4096, 256, 0, stream>>>(W_UV, w_uv_bf);
    // 7. RoPE (q in place fp32; kr -> bf16)
    rope_kernel<<<8192, 256, 0, stream>>>(q_raw, kr, kr_bf, offp);
    // 8. MFMA flash -> ctx (fp32)
    flash_mfma<<<dim3(32, 32), blk, 0, stream>>>(
        q_raw, c_kv_bf, c_kv_T, kr_bf, w_uk_bf, w_uv_bf, offp, ctx);
    // 9. out = ctx @ W_O^T
    gemm_nt<<<dim3(2048/64, 4096/64), blk, 0, stream>>>(
        ctx, W_O, out, 4096, 2048, 2048, 2048, 2048, 2048);
}

// Round 5
// 1530.847 us; speedup vs baseline: 21.0593x; 2.3839x over previous
//
#include <hip/hip_runtime.h>
#include <hip/hip_bf16.h>
#include <math.h>

#define B_    2
#define S_    2048
#define DIN   2048
#define DOUT  2048
#define H_    16
#define RD_   64
#define L_    512
#define HD_   128
#define BS_   (B_*S_)   // 4096

typedef __attribute__((ext_vector_type(8))) short bf16x8;
typedef __attribute__((ext_vector_type(4))) float f32x4;

__device__ __forceinline__ short f2bs(float f) {
    __hip_bfloat16 h = __float2bfloat16(f);
    return *reinterpret_cast<short*>(&h);
}
__device__ __forceinline__ float bs2f(short s) {
    unsigned u = ((unsigned)(unsigned short)s) << 16;
    return __uint_as_float(u);
}

// ---------------------------------------------------------------------------
// fp32 -> bf16 cast, 8 elems/thread. n8 = n/8.
// ---------------------------------------------------------------------------
__global__ __launch_bounds__(256) void cast_bf(const float* __restrict__ in,
                                               short* __restrict__ out, int n8)
{
    int i = blockIdx.x * 256 + threadIdx.x;
    if (i >= n8) return;
    float4 a = ((const float4*)in)[i*2], b = ((const float4*)in)[i*2+1];
    bf16x8 t;
    t[0]=f2bs(a.x); t[1]=f2bs(a.y); t[2]=f2bs(a.z); t[3]=f2bs(a.w);
    t[4]=f2bs(b.x); t[5]=f2bs(b.y); t[6]=f2bs(b.z); t[7]=f2bs(b.w);
    ((bf16x8*)out)[i] = t;
}

// ---------------------------------------------------------------------------
// bf16 MFMA NT GEMM: C[m][n] = sum_k A[m][k]*B[n][k].  M=grid.y*128, K%32==0.
// 256 thr = 4 waves (2x2 of 64x64), 16x16x32 MFMA, acc fp32.
// LDS tiles [128][32] bf16 at pitch 40 shorts -> conflict-free b128 frag reads
// (bank = (row*20 + quad*4)%32, each 8-lane phase covers all 32 banks).
// Writes fp32 (Cf) or bf16 (Cb).
// ---------------------------------------------------------------------------
__global__ __launch_bounds__(256, 4) void gemm_bf(
    const short* __restrict__ A, const short* __restrict__ Bw,
    float* __restrict__ Cf, short* __restrict__ Cb, int N, int K)
{
    __shared__ short As[128*40];
    __shared__ short Bs[128*40];
    const int tid = threadIdx.x;
    const int m0 = blockIdx.y << 7, n0 = blockIdx.x << 7;
    const int w = tid >> 6, lane = tid & 63;
    const int quad = lane >> 4, n16 = lane & 15;
    const int mw = (w & 1) << 6, nw = (w >> 1) << 6;

    f32x4 acc[4][4];
    #pragma unroll
    for (int mt = 0; mt < 4; mt++)
        #pragma unroll
        for (int nt = 0; nt < 4; nt++) acc[mt][nt] = (f32x4){0.f,0.f,0.f,0.f};

    for (int k0 = 0; k0 < K; k0 += 32) {
        #pragma unroll
        for (int i = 0; i < 2; i++) {
            int c = i*256 + tid;
            int m = c >> 2, kc = c & 3;
            *(bf16x8*)(As + m*40 + kc*8) =
                *(const bf16x8*)(A + (long long)(m0 + m)*K + k0 + kc*8);
            *(bf16x8*)(Bs + m*40 + kc*8) =
                *(const bf16x8*)(Bw + (long long)(n0 + m)*K + k0 + kc*8);
        }
        __syncthreads();
        bf16x8 af[4], bfr[4];
        #pragma unroll
        for (int t = 0; t < 4; t++) {
            af[t]  = *(const bf16x8*)(As + (mw + t*16 + n16)*40 + quad*8);
            bfr[t] = *(const bf16x8*)(Bs + (nw + t*16 + n16)*40 + quad*8);
        }
        #pragma unroll
        for (int mt = 0; mt < 4; mt++)
            #pragma unroll
            for (int nt = 0; nt < 4; nt++)
                acc[mt][nt] = __builtin_amdgcn_mfma_f32_16x16x32_bf16(
                                  af[mt], bfr[nt], acc[mt][nt], 0, 0, 0);
        __syncthreads();
    }

    #pragma unroll
    for (int mt = 0; mt < 4; mt++)
        #pragma unroll
        for (int nt = 0; nt < 4; nt++)
            #pragma unroll
            for (int r = 0; r < 4; r++) {
                long long row = m0 + mw + mt*16 + quad*4 + r;
                int col = n0 + nw + nt*16 + n16;
                if (Cf) Cf[row*(long long)N + col] = acc[mt][nt][r];
                else    Cb[row*(long long)N + col] = f2bs(acc[mt][nt][r]);
            }
}

// ---------------------------------------------------------------------------
// RMSNorm rows of 512 (fp32 in) -> bf16 out
// ---------------------------------------------------------------------------
__global__ __launch_bounds__(256) void rmsnorm_bf(const float* __restrict__ ckv,
                                                  const float* __restrict__ w,
                                                  short* __restrict__ out)
{
    const int row = blockIdx.x;
    const int tid = threadIdx.x;
    const float* p = ckv + (long long)row * L_;
    float v0 = p[tid], v1 = p[tid + 256];
    float ss = v0 * v0 + v1 * v1;
    #pragma unroll
    for (int o = 32; o >= 1; o >>= 1) ss += __shfl_xor(ss, o);
    __shared__ float wsum[4];
    if ((tid & 63) == 0) wsum[tid >> 6] = ss;
    __syncthreads();
    float tot = wsum[0] + wsum[1] + wsum[2] + wsum[3];
    float scale = rsqrtf(tot * (1.0f / (float)L_) + 1e-6f);
    out[(long long)row * L_ + tid]       = f2bs(v0 * scale * w[tid]);
    out[(long long)row * L_ + tid + 256] = f2bs(v1 * scale * w[tid + 256]);
}

// ---------------------------------------------------------------------------
// c_kv_T[b][n][t] = c_kv_bf[b][t][n]   grid (S/64, 512/64, B)
// ---------------------------------------------------------------------------
__global__ __launch_bounds__(256) void ckv_transpose(const short* __restrict__ in,
                                                     short* __restrict__ out)
{
    __shared__ short tile[64][72];
    const int b = blockIdx.z, t0 = blockIdx.x * 64, n0 = blockIdx.y * 64;
    const int tid = threadIdx.x;
    #pragma unroll
    for (int i = 0; i < 16; i++) {
        int idx = i*256 + tid, r = idx >> 6, c = idx & 63;
        tile[r][c] = in[((long long)b*S_ + t0 + r)*512 + n0 + c];
    }
    __syncthreads();
    #pragma unroll
    for (int i = 0; i < 16; i++) {
        int idx = i*256 + tid, r = idx >> 6, c = idx & 63;
        out[((long long)b*512 + n0 + r)*2048 + t0 + c] = tile[c][r];
    }
}

// ---------------------------------------------------------------------------
// w_uk_bf[h][l][d] = bf16(W_UK[h*HD + d][l])
// ---------------------------------------------------------------------------
__global__ __launch_bounds__(256) void transpose_wuk_bf(const float* __restrict__ W_UK,
                                                        short* __restrict__ w_uk_bf)
{
    long long idx = (long long)blockIdx.x * 256 + threadIdx.x;  // H*L*HD
    int d = (int)(idx % HD_);
    long long t = idx / HD_;
    int l = (int)(t % L_);
    int h = (int)(t / L_);
    w_uk_bf[idx] = f2bs(W_UK[(long long)(h * HD_ + d) * L_ + l]);
}

__global__ __launch_bounds__(256) void cast_wuv(const float* __restrict__ in,
                                                short* __restrict__ out)
{
    long long idx = (long long)blockIdx.x * 256 + threadIdx.x;  // 2048*512
    out[idx] = f2bs(in[idx]);
}

// ---------------------------------------------------------------------------
// RoPE in place on bf16 q (cols 2048+h*64..) and bf16 kr (head-major cols)
// ---------------------------------------------------------------------------
__global__ __launch_bounds__(256) void rope_kernel(short* __restrict__ q_bf,
                                                   short* __restrict__ kr_bf,
                                                   const int* __restrict__ offp)
{
    const int offset = offp[0];
    long long idx = (long long)blockIdx.x * 256 + threadIdx.x;  // (B*S)*H*32
    int r = (int)(idx & 31);
    long long t = idx >> 5;
    int h = (int)(t % H_);
    long long m = t / H_;
    int s = (int)(m % S_);

    float inv = (float)exp(-9.210340371976184 * ((double)r / 32.0));
    float ang = (float)(offset + s) * inv;
    float sn, cs;
    sincosf(ang, &sn, &cs);

    short* q = q_bf + m * 3072 + DOUT + h * RD_;
    float x1 = bs2f(q[r]), x2 = bs2f(q[r + 32]);
    q[r]      = f2bs(x1 * cs - x2 * sn);
    q[r + 32] = f2bs(x2 * cs + x1 * sn);

    short* kk = kr_bf + m * (H_ * RD_) + h * RD_;
    x1 = bs2f(kk[r]); x2 = bs2f(kk[r + 32]);
    kk[r]      = f2bs(x1 * cs - x2 * sn);
    kk[r + 32] = f2bs(x2 * cs + x1 * sn);
}

// ---------------------------------------------------------------------------
// MFMA flash latent attention v2.
// Grid (S/128, B*H), 512 thr = 8 waves; wave w owns q-rows w*16..w*16+15.
// 64-token K/V tiles. LDS 149,504 B (1 block/CU):
//   K-tile [64][584] (content 0..511, rope 512..575) at 0
//   V-tile [512][72] at short-offset 37376
//   P (wave-private [16][72] @ w*1152) overlays K rows 0..15
//   prologue Q [128][584] / epilogue O [128][520] overlay everything.
// __launch_bounds__(512,2) -> 256-VGPR budget fits Oacc(128)+qf(72)+temps.
// ---------------------------------------------------------------------------
__global__ __launch_bounds__(512, 2) void flash_mfma(
    const short* __restrict__ q_bf,     // [BS][3072] bf16, rope cols rotated
    const short* __restrict__ c_kv_bf,  // [BS][512]  bf16
    const short* __restrict__ c_kv_T,   // [B][512][2048] bf16
    const short* __restrict__ kr_bf,    // [BS][1024] bf16, rotated
    const short* __restrict__ w_uk_bf,  // [H][512][128] bf16
    const short* __restrict__ w_uv_bf,  // [2048][512] bf16
    const int* __restrict__ offp,
    short* __restrict__ ctx_bf)         // [BS][2048] bf16
{
    __shared__ short lds[74752];
    short* Vt = lds + 37376;
    const int offset = offp[0];
    const int bh = blockIdx.y;
    const int b = bh >> 4, h = bh & 15;
    const int r0 = (int)(gridDim.x - 1 - blockIdx.x) * 128;  // longest first
    const int tid = threadIdx.x;
    const int w = tid >> 6, lane = tid & 63;
    const int quad = lane >> 4, n16 = lane & 15;
    const float scale = rsqrtf((float)(HD_ + RD_));

    // ---- prologue: q_abs = q_content @ w_uk^T (MFMA) -> Q tile in LDS ----
    {
        const long long qrow = (long long)b*S_ + r0 + w*16 + n16;
        const short* qp = q_bf + qrow*3072 + h*HD_ + quad*8;
        bf16x8 qc[4];
        #pragma unroll
        for (int ks = 0; ks < 4; ks++) qc[ks] = *(const bf16x8*)(qp + ks*32);
        #pragma unroll 4
        for (int v = 0; v < 32; v++) {
            f32x4 a = {0.f,0.f,0.f,0.f};
            const short* wp = w_uk_bf + ((long long)(h*512 + v*16 + n16) << 7) + quad*8;
            #pragma unroll
            for (int ks = 0; ks < 4; ks++)
                a = __builtin_amdgcn_mfma_f32_16x16x32_bf16(
                        qc[ks], *(const bf16x8*)(wp + ks*32), a, 0, 0, 0);
            #pragma unroll
            for (int r = 0; r < 4; r++)
                lds[(w*16 + quad*4 + r)*584 + v*16 + n16] = f2bs(a[r]);
        }
        // rope cols 512..575 (straight bf16 copy)
        #pragma unroll
        for (int i = 0; i < 16; i++) {
            int idx = i*512 + tid, rr = idx >> 6, cc = idx & 63;
            lds[rr*584 + 512 + cc] =
                q_bf[((long long)b*S_ + r0 + rr)*3072 + DOUT + h*RD_ + cc];
        }
    }
    __syncthreads();
    bf16x8 qf[18];
    {
        const int qb = (w*16 + n16)*584 + quad*8;
        #pragma unroll
        for (int ks = 0; ks < 18; ks++)
            qf[ks] = *(const bf16x8*)(lds + qb + ks*32);
    }

    f32x4 Oacc[32];
    #pragma unroll
    for (int v = 0; v < 32; v++) Oacc[v] = (f32x4){0.f,0.f,0.f,0.f};
    float mrun[4] = {-INFINITY,-INFINITY,-INFINITY,-INFINITY};
    float lrun[4] = {0.f,0.f,0.f,0.f};

    int tmax = r0 + 128 + offset;
    if (tmax > S_) tmax = S_;

    for (int t0 = 0; t0 < tmax; t0 += 64) {
        __syncthreads();   // prior-iter P/V reads (and prologue/Q reads) done
        // K content [64][512]
        #pragma unroll
        for (int i = 0; i < 8; i++) {
            int c = i*512 + tid, row = c >> 6, cc = c & 63;
            *(bf16x8*)(lds + row*584 + cc*8) =
                *(const bf16x8*)(c_kv_bf + (((long long)b*S_ + t0 + row) << 9) + cc*8);
        }
        // K rope [64][64]
        {
            int row = tid >> 3, cz = tid & 7;
            *(bf16x8*)(lds + row*584 + 512 + cz*8) =
                *(const bf16x8*)(kr_bf + (((long long)b*S_ + t0 + row) << 10) + h*RD_ + cz*8);
        }
        // V [512][64]
        #pragma unroll
        for (int i = 0; i < 8; i++) {
            int c = i*512 + tid, n = c >> 3, tc = c & 7;
            *(bf16x8*)(Vt + n*72 + tc*8) =
                *(const bf16x8*)(c_kv_T + (((long long)b*512 + n) << 11) + t0 + tc*8);
        }
        __syncthreads();

        // scores: 4 token-tiles of 16
        f32x4 Sf[4];
        #pragma unroll
        for (int nt = 0; nt < 4; nt++) {
            f32x4 a = {0.f,0.f,0.f,0.f};
            const int kb = (nt*16 + n16)*584 + quad*8;
            #pragma unroll
            for (int ks = 0; ks < 18; ks++)
                a = __builtin_amdgcn_mfma_f32_16x16x32_bf16(
                        qf[ks], *(const bf16x8*)(lds + kb + ks*32), a, 0, 0, 0);
            Sf[nt] = a;
        }

        float p[4][4], alpha[4];
        #pragma unroll
        for (int r = 0; r < 4; r++) {
            int srow = r0 + w*16 + quad*4 + r;
            float e[4], tm = -INFINITY;
            #pragma unroll
            for (int nt = 0; nt < 4; nt++) {
                int t = t0 + nt*16 + n16;
                float s = (t <= srow + offset) ? Sf[nt][r]*scale : -INFINITY;
                e[nt] = s; tm = fmaxf(tm, s);
            }
            tm = fmaxf(tm, __shfl_xor(tm, 1));
            tm = fmaxf(tm, __shfl_xor(tm, 2));
            tm = fmaxf(tm, __shfl_xor(tm, 4));
            tm = fmaxf(tm, __shfl_xor(tm, 8));
            float mn = fmaxf(mrun[r], tm);
            float al = __expf(mrun[r] - mn);
            float ps = 0.f;
            #pragma unroll
            for (int nt = 0; nt < 4; nt++) { e[nt] = __expf(e[nt] - mn); ps += e[nt]; }
            ps += __shfl_xor(ps, 1);
            ps += __shfl_xor(ps, 2);
            ps += __shfl_xor(ps, 4);
            ps += __shfl_xor(ps, 8);
            lrun[r] = lrun[r]*al + ps;
            mrun[r] = mn;
            alpha[r] = al;
            p[0][r] = e[0]; p[1][r] = e[1]; p[2][r] = e[2]; p[3][r] = e[3];
        }
        #pragma unroll
        for (int v = 0; v < 32; v++) {
            Oacc[v][0] *= alpha[0]; Oacc[v][1] *= alpha[1];
            Oacc[v][2] *= alpha[2]; Oacc[v][3] *= alpha[3];
        }
        __syncthreads();   // all waves done reading K before P overlays it

        const int wb = w*1152;
        #pragma unroll
        for (int r = 0; r < 4; r++)
            #pragma unroll
            for (int nt = 0; nt < 4; nt++)
                lds[wb + (quad*4 + r)*72 + nt*16 + n16] = f2bs(p[nt][r]);
        bf16x8 pf0 = *(const bf16x8*)(lds + wb + n16*72 + quad*8);
        bf16x8 pf1 = *(const bf16x8*)(lds + wb + n16*72 + 32 + quad*8);
        #pragma unroll
        for (int v = 0; v < 32; v++) {
            const short* vb = Vt + (v*16 + n16)*72 + quad*8;
            Oacc[v] = __builtin_amdgcn_mfma_f32_16x16x32_bf16(
                          pf0, *(const bf16x8*)vb, Oacc[v], 0, 0, 0);
            Oacc[v] = __builtin_amdgcn_mfma_f32_16x16x32_bf16(
                          pf1, *(const bf16x8*)(vb + 32), Oacc[v], 0, 0, 0);
        }
    }

    // ---- epilogue: ctx = (O/l) @ W_UV^T via MFMA ----
    __syncthreads();
    float inv[4];
    #pragma unroll
    for (int r = 0; r < 4; r++) inv[r] = 1.0f / lrun[r];
    #pragma unroll
    for (int v = 0; v < 32; v++)
        #pragma unroll
        for (int r = 0; r < 4; r++)
            lds[(w*16 + quad*4 + r)*520 + v*16 + n16] = f2bs(Oacc[v][r]*inv[r]);
    __syncthreads();
    f32x4 cacc[8];
    #pragma unroll
    for (int d = 0; d < 8; d++) cacc[d] = (f32x4){0.f,0.f,0.f,0.f};
    const int ob = (w*16 + n16)*520 + quad*8;
    for (int ks = 0; ks < 16; ks++) {
        bf16x8 of = *(const bf16x8*)(lds + ob + ks*32);
        #pragma unroll
        for (int d = 0; d < 8; d++) {
            const short* wp = w_uv_bf + (((long long)(h*HD_ + d*16 + n16)) << 9)
                            + ks*32 + quad*8;
            cacc[d] = __builtin_amdgcn_mfma_f32_16x16x32_bf16(
                          of, *(const bf16x8*)wp, cacc[d], 0, 0, 0);
        }
    }
    #pragma unroll
    for (int d = 0; d < 8; d++)
        #pragma unroll
        for (int r = 0; r < 4; r++) {
            long long row = (long long)b*S_ + r0 + w*16 + quad*4 + r;
            ctx_bf[row*2048 + h*HD_ + d*16 + n16] = f2bs(cacc[d][r]);
        }
}

// ---------------------------------------------------------------------------
extern "C" void kernel_launch(void* const* d_in, const int* in_sizes, int n_in,
                              void* d_out, int out_size, void* d_ws, size_t ws_size,
                              hipStream_t stream)
{
    const float* x       = (const float*)d_in[0];
    const float* W_DKV   = (const float*)d_in[1];
    const float* W_KRope = (const float*)d_in[2];
    const float* W_Q     = (const float*)d_in[3];
    const float* W_UK    = (const float*)d_in[4];
    const float* W_UV    = (const float*)d_in[5];
    const float* W_O     = (const float*)d_in[6];
    const float* kvnw    = (const float*)d_in[7];
    const int*   offp    = (const int*)d_in[8];
    float* out = (float*)d_out;

    float* ws = (float*)d_ws;
    float* c_kv    = ws;                        // 2,097,152 f
    short* x_bf    = (short*)(c_kv + 2097152);  // 8,388,608
    short* q_bf    = x_bf    + 8388608;         // 12,582,912
    short* kr_bf   = q_bf    + 12582912;        // 4,194,304
    short* c_kv_bf = kr_bf   + 4194304;         // 2,097,152
    short* c_kv_T  = c_kv_bf + 2097152;         // 2,097,152
    short* w_uk_bf = c_kv_T  + 2097152;         // 1,048,576
    short* w_uv_bf = w_uk_bf + 1048576;         // 1,048,576
    short* wdkv_bf = w_uv_bf + 1048576;         // 1,048,576
    short* wkr_bf  = wdkv_bf + 1048576;         // 2,097,152
    short* wq_bf   = wkr_bf  + 2097152;         // 6,291,456
    short* wo_bf   = wq_bf   + 6291456;         // 4,194,304
    short* ctx_bf  = wo_bf   + 4194304;         // 8,388,608
    // total ~115 MiB

    dim3 blk(256);

    // casts to bf16
    cast_bf<<<4096, blk, 0, stream>>>(x, x_bf, 1048576);
    cast_bf<<<512,  blk, 0, stream>>>(W_DKV, wdkv_bf, 131072);
    cast_bf<<<1024, blk, 0, stream>>>(W_KRope, wkr_bf, 262144);
    cast_bf<<<3072, blk, 0, stream>>>(W_Q, wq_bf, 786432);
    cast_bf<<<2048, blk, 0, stream>>>(W_O, wo_bf, 524288);
    transpose_wuk_bf<<<4096, blk, 0, stream>>>(W_UK, w_uk_bf);
    cast_wuv<<<4096, blk, 0, stream>>>(W_UV, w_uv_bf);

    // projections (bf16 MFMA)
    gemm_bf<<<dim3(512/128, 32), blk, 0, stream>>>(
        x_bf, wdkv_bf, c_kv, nullptr, 512, 2048);
    rmsnorm_bf<<<4096, blk, 0, stream>>>(c_kv, kvnw, c_kv_bf);
    ckv_transpose<<<dim3(32, 8, 2), blk, 0, stream>>>(c_kv_bf, c_kv_T);
    gemm_bf<<<dim3(1024/128, 32), blk, 0, stream>>>(
        x_bf, wkr_bf, nullptr, kr_bf, 1024, 2048);
    gemm_bf<<<dim3(3072/128, 32), blk, 0, stream>>>(
        x_bf, wq_bf, nullptr, q_bf, 3072, 2048);

    // RoPE in place (bf16)
    rope_kernel<<<8192, blk, 0, stream>>>(q_bf, kr_bf, offp);

    // fused flash latent attention -> ctx (bf16)
    flash_mfma<<<dim3(S_/128, B_*H_), dim3(512), 0, stream>>>(
        q_bf, c_kv_bf, c_kv_T, kr_bf, w_uk_bf, w_uv_bf, offp, ctx_bf);

    // out = ctx @ W_O^T (fp32 out)
    gemm_bf<<<dim3(2048/128, 32), blk, 0, stream>>>(
        ctx_bf, wo_bf, out, nullptr, 2048, 2048);
}

// Round 6
// 1528.536 us; speedup vs baseline: 21.0911x; 1.0015x over previous
//
#include <hip/hip_runtime.h>
#include <hip/hip_bf16.h>
#include <math.h>

#define B_    2
#define S_    2048
#define DIN   2048
#define DOUT  2048
#define H_    16
#define RD_   64
#define L_    512
#define HD_   128
#define BS_   (B_*S_)   // 4096

typedef __attribute__((ext_vector_type(8))) short bf16x8;
typedef __attribute__((ext_vector_type(4))) float f32x4;

__device__ __forceinline__ short f2bs(float f) {
    __hip_bfloat16 h = __float2bfloat16(f);
    return *reinterpret_cast<short*>(&h);
}
__device__ __forceinline__ float bs2f(short s) {
    unsigned u = ((unsigned)(unsigned short)s) << 16;
    return __uint_as_float(u);
}

// ---------------------------------------------------------------------------
// fp32 -> bf16 cast, 8 elems/thread. n8 = n/8.
// ---------------------------------------------------------------------------
__global__ __launch_bounds__(256) void cast_bf(const float* __restrict__ in,
                                               short* __restrict__ out, int n8)
{
    int i = blockIdx.x * 256 + threadIdx.x;
    if (i >= n8) return;
    float4 a = ((const float4*)in)[i*2], b = ((const float4*)in)[i*2+1];
    bf16x8 t;
    t[0]=f2bs(a.x); t[1]=f2bs(a.y); t[2]=f2bs(a.z); t[3]=f2bs(a.w);
    t[4]=f2bs(b.x); t[5]=f2bs(b.y); t[6]=f2bs(b.z); t[7]=f2bs(b.w);
    ((bf16x8*)out)[i] = t;
}

// ---------------------------------------------------------------------------
// bf16 MFMA NT GEMM: C[m][n] = sum_k A[m][k]*B[n][k].  M=grid.y*128, K%32==0.
// 256 thr = 4 waves (2x2 of 64x64), 16x16x32 MFMA, acc fp32.
// LDS tiles [128][32] bf16 at pitch 40 shorts -> conflict-free b128 frag reads.
// Writes fp32 (Cf) or bf16 (Cb).
// ---------------------------------------------------------------------------
__global__ __launch_bounds__(256, 4) void gemm_bf(
    const short* __restrict__ A, const short* __restrict__ Bw,
    float* __restrict__ Cf, short* __restrict__ Cb, int N, int K)
{
    __shared__ short As[128*40];
    __shared__ short Bs[128*40];
    const int tid = threadIdx.x;
    const int m0 = blockIdx.y << 7, n0 = blockIdx.x << 7;
    const int w = tid >> 6, lane = tid & 63;
    const int quad = lane >> 4, n16 = lane & 15;
    const int mw = (w & 1) << 6, nw = (w >> 1) << 6;

    f32x4 acc[4][4];
    #pragma unroll
    for (int mt = 0; mt < 4; mt++)
        #pragma unroll
        for (int nt = 0; nt < 4; nt++) acc[mt][nt] = (f32x4){0.f,0.f,0.f,0.f};

    for (int k0 = 0; k0 < K; k0 += 32) {
        #pragma unroll
        for (int i = 0; i < 2; i++) {
            int c = i*256 + tid;
            int m = c >> 2, kc = c & 3;
            *(bf16x8*)(As + m*40 + kc*8) =
                *(const bf16x8*)(A + (long long)(m0 + m)*K + k0 + kc*8);
            *(bf16x8*)(Bs + m*40 + kc*8) =
                *(const bf16x8*)(Bw + (long long)(n0 + m)*K + k0 + kc*8);
        }
        __syncthreads();
        bf16x8 af[4], bfr[4];
        #pragma unroll
        for (int t = 0; t < 4; t++) {
            af[t]  = *(const bf16x8*)(As + (mw + t*16 + n16)*40 + quad*8);
            bfr[t] = *(const bf16x8*)(Bs + (nw + t*16 + n16)*40 + quad*8);
        }
        #pragma unroll
        for (int mt = 0; mt < 4; mt++)
            #pragma unroll
            for (int nt = 0; nt < 4; nt++)
                acc[mt][nt] = __builtin_amdgcn_mfma_f32_16x16x32_bf16(
                                  af[mt], bfr[nt], acc[mt][nt], 0, 0, 0);
        __syncthreads();
    }

    #pragma unroll
    for (int mt = 0; mt < 4; mt++)
        #pragma unroll
        for (int nt = 0; nt < 4; nt++)
            #pragma unroll
            for (int r = 0; r < 4; r++) {
                long long row = m0 + mw + mt*16 + quad*4 + r;
                int col = n0 + nw + nt*16 + n16;
                if (Cf) Cf[row*(long long)N + col] = acc[mt][nt][r];
                else    Cb[row*(long long)N + col] = f2bs(acc[mt][nt][r]);
            }
}

// ---------------------------------------------------------------------------
// RMSNorm rows of 512 (fp32 in) -> bf16 out
// ---------------------------------------------------------------------------
__global__ __launch_bounds__(256) void rmsnorm_bf(const float* __restrict__ ckv,
                                                  const float* __restrict__ w,
                                                  short* __restrict__ out)
{
    const int row = blockIdx.x;
    const int tid = threadIdx.x;
    const float* p = ckv + (long long)row * L_;
    float v0 = p[tid], v1 = p[tid + 256];
    float ss = v0 * v0 + v1 * v1;
    #pragma unroll
    for (int o = 32; o >= 1; o >>= 1) ss += __shfl_xor(ss, o);
    __shared__ float wsum[4];
    if ((tid & 63) == 0) wsum[tid >> 6] = ss;
    __syncthreads();
    float tot = wsum[0] + wsum[1] + wsum[2] + wsum[3];
    float scale = rsqrtf(tot * (1.0f / (float)L_) + 1e-6f);
    out[(long long)row * L_ + tid]       = f2bs(v0 * scale * w[tid]);
    out[(long long)row * L_ + tid + 256] = f2bs(v1 * scale * w[tid + 256]);
}

// ---------------------------------------------------------------------------
// c_kv_T[b][n][t] = c_kv_bf[b][t][n]   grid (S/64, 512/64, B)
// ---------------------------------------------------------------------------
__global__ __launch_bounds__(256) void ckv_transpose(const short* __restrict__ in,
                                                     short* __restrict__ out)
{
    __shared__ short tile[64][72];
    const int b = blockIdx.z, t0 = blockIdx.x * 64, n0 = blockIdx.y * 64;
    const int tid = threadIdx.x;
    #pragma unroll
    for (int i = 0; i < 16; i++) {
        int idx = i*256 + tid, r = idx >> 6, c = idx & 63;
        tile[r][c] = in[((long long)b*S_ + t0 + r)*512 + n0 + c];
    }
    __syncthreads();
    #pragma unroll
    for (int i = 0; i < 16; i++) {
        int idx = i*256 + tid, r = idx >> 6, c = idx & 63;
        out[((long long)b*512 + n0 + r)*2048 + t0 + c] = tile[c][r];
    }
}

// ---------------------------------------------------------------------------
// w_uk_bf[h][l][d] = bf16(W_UK[h*HD + d][l])
// ---------------------------------------------------------------------------
__global__ __launch_bounds__(256) void transpose_wuk_bf(const float* __restrict__ W_UK,
                                                        short* __restrict__ w_uk_bf)
{
    long long idx = (long long)blockIdx.x * 256 + threadIdx.x;  // H*L*HD
    int d = (int)(idx % HD_);
    long long t = idx / HD_;
    int l = (int)(t % L_);
    int h = (int)(t / L_);
    w_uk_bf[idx] = f2bs(W_UK[(long long)(h * HD_ + d) * L_ + l]);
}

__global__ __launch_bounds__(256) void cast_wuv(const float* __restrict__ in,
                                                short* __restrict__ out)
{
    long long idx = (long long)blockIdx.x * 256 + threadIdx.x;  // 2048*512
    out[idx] = f2bs(in[idx]);
}

// ---------------------------------------------------------------------------
// RoPE in place on bf16 q (cols 2048+h*64..) and bf16 kr (head-major cols)
// ---------------------------------------------------------------------------
__global__ __launch_bounds__(256) void rope_kernel(short* __restrict__ q_bf,
                                                   short* __restrict__ kr_bf,
                                                   const int* __restrict__ offp)
{
    const int offset = offp[0];
    long long idx = (long long)blockIdx.x * 256 + threadIdx.x;  // (B*S)*H*32
    int r = (int)(idx & 31);
    long long t = idx >> 5;
    int h = (int)(t % H_);
    long long m = t / H_;
    int s = (int)(m % S_);

    float inv = (float)exp(-9.210340371976184 * ((double)r / 32.0));
    float ang = (float)(offset + s) * inv;
    float sn, cs;
    sincosf(ang, &sn, &cs);

    short* q = q_bf + m * 3072 + DOUT + h * RD_;
    float x1 = bs2f(q[r]), x2 = bs2f(q[r + 32]);
    q[r]      = f2bs(x1 * cs - x2 * sn);
    q[r + 32] = f2bs(x2 * cs + x1 * sn);

    short* kk = kr_bf + m * (H_ * RD_) + h * RD_;
    x1 = bs2f(kk[r]); x2 = bs2f(kk[r + 32]);
    kk[r]      = f2bs(x1 * cs - x2 * sn);
    kk[r + 32] = f2bs(x2 * cs + x1 * sn);
}

// ---------------------------------------------------------------------------
// MFMA flash latent attention v2.1.
// Grid (S/128, B*H), 512 thr = 8 waves; wave w owns q-rows w*16..w*16+15.
// 64-token K/V tiles. LDS 149,504 B -> occupancy is 1 block/CU = 2 waves/EU.
// amdgpu_waves_per_eu(2,2) pins the allocator to the 256-VGPR budget so the
// ~240-reg live state (Oacc 128 + qf 72 + temps) fits WITHOUT scratch spill.
// (R5 evidence: __launch_bounds__(512,2) alone -> VGPR_Count=128 + 515 MB/disp
// spill writes; launch_bounds second arg is only a *min* waves/EU.)
// ---------------------------------------------------------------------------
__global__ __launch_bounds__(512)
__attribute__((amdgpu_waves_per_eu(2, 2)))
void flash_mfma(
    const short* __restrict__ q_bf,     // [BS][3072] bf16, rope cols rotated
    const short* __restrict__ c_kv_bf,  // [BS][512]  bf16
    const short* __restrict__ c_kv_T,   // [B][512][2048] bf16
    const short* __restrict__ kr_bf,    // [BS][1024] bf16, rotated
    const short* __restrict__ w_uk_bf,  // [H][512][128] bf16
    const short* __restrict__ w_uv_bf,  // [2048][512] bf16
    const int* __restrict__ offp,
    short* __restrict__ ctx_bf)         // [BS][2048] bf16
{
    __shared__ short lds[74752];
    short* Vt = lds + 37376;
    const int offset = offp[0];
    const int bh = blockIdx.y;
    const int b = bh >> 4, h = bh & 15;
    const int r0 = (int)(gridDim.x - 1 - blockIdx.x) * 128;  // longest first
    const int tid = threadIdx.x;
    const int w = tid >> 6, lane = tid & 63;
    const int quad = lane >> 4, n16 = lane & 15;
    const float scale = rsqrtf((float)(HD_ + RD_));

    // ---- prologue: q_abs = q_content @ w_uk^T (MFMA) -> Q tile in LDS ----
    {
        const long long qrow = (long long)b*S_ + r0 + w*16 + n16;
        const short* qp = q_bf + qrow*3072 + h*HD_ + quad*8;
        bf16x8 qc[4];
        #pragma unroll
        for (int ks = 0; ks < 4; ks++) qc[ks] = *(const bf16x8*)(qp + ks*32);
        #pragma unroll 4
        for (int v = 0; v < 32; v++) {
            f32x4 a = {0.f,0.f,0.f,0.f};
            const short* wp = w_uk_bf + ((long long)(h*512 + v*16 + n16) << 7) + quad*8;
            #pragma unroll
            for (int ks = 0; ks < 4; ks++)
                a = __builtin_amdgcn_mfma_f32_16x16x32_bf16(
                        qc[ks], *(const bf16x8*)(wp + ks*32), a, 0, 0, 0);
            #pragma unroll
            for (int r = 0; r < 4; r++)
                lds[(w*16 + quad*4 + r)*584 + v*16 + n16] = f2bs(a[r]);
        }
        // rope cols 512..575 (straight bf16 copy)
        #pragma unroll
        for (int i = 0; i < 16; i++) {
            int idx = i*512 + tid, rr = idx >> 6, cc = idx & 63;
            lds[rr*584 + 512 + cc] =
                q_bf[((long long)b*S_ + r0 + rr)*3072 + DOUT + h*RD_ + cc];
        }
    }
    __syncthreads();
    bf16x8 qf[18];
    {
        const int qb = (w*16 + n16)*584 + quad*8;
        #pragma unroll
        for (int ks = 0; ks < 18; ks++)
            qf[ks] = *(const bf16x8*)(lds + qb + ks*32);
    }

    f32x4 Oacc[32];
    #pragma unroll
    for (int v = 0; v < 32; v++) Oacc[v] = (f32x4){0.f,0.f,0.f,0.f};
    float mrun[4] = {-INFINITY,-INFINITY,-INFINITY,-INFINITY};
    float lrun[4] = {0.f,0.f,0.f,0.f};

    int tmax = r0 + 128 + offset;
    if (tmax > S_) tmax = S_;

    for (int t0 = 0; t0 < tmax; t0 += 64) {
        __syncthreads();   // prior-iter P/V reads (and prologue/Q reads) done
        // K content [64][512]
        #pragma unroll
        for (int i = 0; i < 8; i++) {
            int c = i*512 + tid, row = c >> 6, cc = c & 63;
            *(bf16x8*)(lds + row*584 + cc*8) =
                *(const bf16x8*)(c_kv_bf + (((long long)b*S_ + t0 + row) << 9) + cc*8);
        }
        // K rope [64][64]
        {
            int row = tid >> 3, cz = tid & 7;
            *(bf16x8*)(lds + row*584 + 512 + cz*8) =
                *(const bf16x8*)(kr_bf + (((long long)b*S_ + t0 + row) << 10) + h*RD_ + cz*8);
        }
        // V [512][64]
        #pragma unroll
        for (int i = 0; i < 8; i++) {
            int c = i*512 + tid, n = c >> 3, tc = c & 7;
            *(bf16x8*)(Vt + n*72 + tc*8) =
                *(const bf16x8*)(c_kv_T + (((long long)b*512 + n) << 11) + t0 + tc*8);
        }
        __syncthreads();

        // scores: 4 token-tiles of 16
        f32x4 Sf[4];
        #pragma unroll
        for (int nt = 0; nt < 4; nt++) {
            f32x4 a = {0.f,0.f,0.f,0.f};
            const int kb = (nt*16 + n16)*584 + quad*8;
            #pragma unroll
            for (int ks = 0; ks < 18; ks++)
                a = __builtin_amdgcn_mfma_f32_16x16x32_bf16(
                        qf[ks], *(const bf16x8*)(lds + kb + ks*32), a, 0, 0, 0);
            Sf[nt] = a;
        }

        float p[4][4], alpha[4];
        #pragma unroll
        for (int r = 0; r < 4; r++) {
            int srow = r0 + w*16 + quad*4 + r;
            float e[4], tm = -INFINITY;
            #pragma unroll
            for (int nt = 0; nt < 4; nt++) {
                int t = t0 + nt*16 + n16;
                float s = (t <= srow + offset) ? Sf[nt][r]*scale : -INFINITY;
                e[nt] = s; tm = fmaxf(tm, s);
            }
            tm = fmaxf(tm, __shfl_xor(tm, 1));
            tm = fmaxf(tm, __shfl_xor(tm, 2));
            tm = fmaxf(tm, __shfl_xor(tm, 4));
            tm = fmaxf(tm, __shfl_xor(tm, 8));
            float mn = fmaxf(mrun[r], tm);
            float al = __expf(mrun[r] - mn);
            float ps = 0.f;
            #pragma unroll
            for (int nt = 0; nt < 4; nt++) { e[nt] = __expf(e[nt] - mn); ps += e[nt]; }
            ps += __shfl_xor(ps, 1);
            ps += __shfl_xor(ps, 2);
            ps += __shfl_xor(ps, 4);
            ps += __shfl_xor(ps, 8);
            lrun[r] = lrun[r]*al + ps;
            mrun[r] = mn;
            alpha[r] = al;
            p[0][r] = e[0]; p[1][r] = e[1]; p[2][r] = e[2]; p[3][r] = e[3];
        }
        #pragma unroll
        for (int v = 0; v < 32; v++) {
            Oacc[v][0] *= alpha[0]; Oacc[v][1] *= alpha[1];
            Oacc[v][2] *= alpha[2]; Oacc[v][3] *= alpha[3];
        }
        __syncthreads();   // all waves done reading K before P overlays it

        const int wb = w*1152;
        #pragma unroll
        for (int r = 0; r < 4; r++)
            #pragma unroll
            for (int nt = 0; nt < 4; nt++)
                lds[wb + (quad*4 + r)*72 + nt*16 + n16] = f2bs(p[nt][r]);
        bf16x8 pf0 = *(const bf16x8*)(lds + wb + n16*72 + quad*8);
        bf16x8 pf1 = *(const bf16x8*)(lds + wb + n16*72 + 32 + quad*8);
        #pragma unroll
        for (int v = 0; v < 32; v++) {
            const short* vb = Vt + (v*16 + n16)*72 + quad*8;
            Oacc[v] = __builtin_amdgcn_mfma_f32_16x16x32_bf16(
                          pf0, *(const bf16x8*)vb, Oacc[v], 0, 0, 0);
            Oacc[v] = __builtin_amdgcn_mfma_f32_16x16x32_bf16(
                          pf1, *(const bf16x8*)(vb + 32), Oacc[v], 0, 0, 0);
        }
    }

    // ---- epilogue: ctx = (O/l) @ W_UV^T via MFMA ----
    __syncthreads();
    float inv[4];
    #pragma unroll
    for (int r = 0; r < 4; r++) inv[r] = 1.0f / lrun[r];
    #pragma unroll
    for (int v = 0; v < 32; v++)
        #pragma unroll
        for (int r = 0; r < 4; r++)
            lds[(w*16 + quad*4 + r)*520 + v*16 + n16] = f2bs(Oacc[v][r]*inv[r]);
    __syncthreads();
    f32x4 cacc[8];
    #pragma unroll
    for (int d = 0; d < 8; d++) cacc[d] = (f32x4){0.f,0.f,0.f,0.f};
    const int ob = (w*16 + n16)*520 + quad*8;
    for (int ks = 0; ks < 16; ks++) {
        bf16x8 of = *(const bf16x8*)(lds + ob + ks*32);
        #pragma unroll
        for (int d = 0; d < 8; d++) {
            const short* wp = w_uv_bf + (((long long)(h*HD_ + d*16 + n16)) << 9)
                            + ks*32 + quad*8;
            cacc[d] = __builtin_amdgcn_mfma_f32_16x16x32_bf16(
                          of, *(const bf16x8*)wp, cacc[d], 0, 0, 0);
        }
    }
    #pragma unroll
    for (int d = 0; d < 8; d++)
        #pragma unroll
        for (int r = 0; r < 4; r++) {
            long long row = (long long)b*S_ + r0 + w*16 + quad*4 + r;
            ctx_bf[row*2048 + h*HD_ + d*16 + n16] = f2bs(cacc[d][r]);
        }
}

// ---------------------------------------------------------------------------
extern "C" void kernel_launch(void* const* d_in, const int* in_sizes, int n_in,
                              void* d_out, int out_size, void* d_ws, size_t ws_size,
                              hipStream_t stream)
{
    const float* x       = (const float*)d_in[0];
    const float* W_DKV   = (const float*)d_in[1];
    const float* W_KRope = (const float*)d_in[2];
    const float* W_Q     = (const float*)d_in[3];
    const float* W_UK    = (const float*)d_in[4];
    const float* W_UV    = (const float*)d_in[5];
    const float* W_O     = (const float*)d_in[6];
    const float* kvnw    = (const float*)d_in[7];
    const int*   offp    = (const int*)d_in[8];
    float* out = (float*)d_out;

    float* ws = (float*)d_ws;
    float* c_kv    = ws;                        // 2,097,152 f
    short* x_bf    = (short*)(c_kv + 2097152);  // 8,388,608
    short* q_bf    = x_bf    + 8388608;         // 12,582,912
    short* kr_bf   = q_bf    + 12582912;        // 4,194,304
    short* c_kv_bf = kr_bf   + 4194304;         // 2,097,152
    short* c_kv_T  = c_kv_bf + 2097152;         // 2,097,152
    short* w_uk_bf = c_kv_T  + 2097152;         // 1,048,576
    short* w_uv_bf = w_uk_bf + 1048576;         // 1,048,576
    short* wdkv_bf = w_uv_bf + 1048576;         // 1,048,576
    short* wkr_bf  = wdkv_bf + 1048576;         // 2,097,152
    short* wq_bf   = wkr_bf  + 2097152;         // 6,291,456
    short* wo_bf   = wq_bf   + 6291456;         // 4,194,304
    short* ctx_bf  = wo_bf   + 4194304;         // 8,388,608
    // total ~115 MiB

    dim3 blk(256);

    // casts to bf16
    cast_bf<<<4096, blk, 0, stream>>>(x, x_bf, 1048576);
    cast_bf<<<512,  blk, 0, stream>>>(W_DKV, wdkv_bf, 131072);
    cast_bf<<<1024, blk, 0, stream>>>(W_KRope, wkr_bf, 262144);
    cast_bf<<<3072, blk, 0, stream>>>(W_Q, wq_bf, 786432);
    cast_bf<<<2048, blk, 0, stream>>>(W_O, wo_bf, 524288);
    transpose_wuk_bf<<<4096, blk, 0, stream>>>(W_UK, w_uk_bf);
    cast_wuv<<<4096, blk, 0, stream>>>(W_UV, w_uv_bf);

    // projections (bf16 MFMA)
    gemm_bf<<<dim3(512/128, 32), blk, 0, stream>>>(
        x_bf, wdkv_bf, c_kv, nullptr, 512, 2048);
    rmsnorm_bf<<<4096, blk, 0, stream>>>(c_kv, kvnw, c_kv_bf);
    ckv_transpose<<<dim3(32, 8, 2), blk, 0, stream>>>(c_kv_bf, c_kv_T);
    gemm_bf<<<dim3(1024/128, 32), blk, 0, stream>>>(
        x_bf, wkr_bf, nullptr, kr_bf, 1024, 2048);
    gemm_bf<<<dim3(3072/128, 32), blk, 0, stream>>>(
        x_bf, wq_bf, nullptr, q_bf, 3072, 2048);

    // RoPE in place (bf16)
    rope_kernel<<<8192, blk, 0, stream>>>(q_bf, kr_bf, offp);

    // fused flash latent attention -> ctx (bf16)
    flash_mfma<<<dim3(S_/128, B_*H_), dim3(512), 0, stream>>>(
        q_bf, c_kv_bf, c_kv_T, kr_bf, w_uk_bf, w_uv_bf, offp, ctx_bf);

    // out = ctx @ W_O^T (fp32 out)
    gemm_bf<<<dim3(2048/128, 32), blk, 0, stream>>>(
        ctx_bf, wo_bf, out, nullptr, 2048, 2048);
}